// Round 1
// baseline (7517.101 us; speedup 1.0000x reference)
//
#include <hip/hip_runtime.h>
#include <hip/hip_bf16.h>
#include <cstdint>
#include <cstddef>

#define T_STEPS 256
#define BATCH   512
#define DIM     512
#define HID     512
#define NQV     8
#define KDIM    1024
#define NPACK   2064   // 32 h-blocks * 64 gate cols + 16 q cols (8 real + 8 pad)
#define ALPHA_C 0.7f

typedef __bf16 bf16x8 __attribute__((ext_vector_type(8)));
typedef float  f32x4  __attribute__((ext_vector_type(4)));

// ---------------- prep kernels ----------------

__global__ void zero_kernel(uint32_t* p, int n) {
    int i = blockIdx.x * 256 + threadIdx.x;
    if (i < n) p[i] = 0u;
}

// Wt layout: (NPACK rows, KDIM cols) bf16, row-major (k contiguous).
// n in [0,2048): j=n>>6 (h-block), c=n&63, gate=c>>4, h=16j+(c&15): Wt[n][k]=W_g[k][h]
// n in [2048,2056): Wt[n][k]=Wq[k][n-2048];  n in [2056,2064): 0
__global__ void pack_w_kernel(const float* __restrict__ Wf, const float* __restrict__ Wi,
                              const float* __restrict__ Wu, const float* __restrict__ Wo,
                              const float* __restrict__ Wq, __bf16* __restrict__ Wt) {
    int idx = blockIdx.x * 256 + threadIdx.x;   // grid covers NPACK*KDIM exactly
    int n = idx >> 10;
    int k = idx & 1023;
    float v = 0.0f;
    if (n < 2048) {
        int j = n >> 6, c = n & 63, g = c >> 4;
        int hh = (j << 4) | (c & 15);
        const float* W = (g == 0) ? Wf : (g == 1) ? Wi : (g == 2) ? Wu : Wo;
        v = W[k * HID + hh];
    } else if (n < 2056) {
        v = Wq[k * NQV + (n - 2048)];
    }
    Wt[idx] = (__bf16)v;
}

// WqhT: (HID, 8) bf16, row h holds Wqh[0..7][h]
__global__ void pack_wqh_kernel(const float* __restrict__ Wqh, __bf16* __restrict__ WqhT) {
    int idx = blockIdx.x * 256 + threadIdx.x;
    if (idx < HID * NQV) {
        int h = idx >> 3, w = idx & 7;
        WqhT[idx] = (__bf16)Wqh[w * HID + h];
    }
}

__global__ void cvt_x_kernel(const float* __restrict__ X, __bf16* __restrict__ Xbf) {
    size_t i = ((size_t)blockIdx.x * 256 + threadIdx.x) * 8;
    float4 a = *(const float4*)(X + i);
    float4 b = *(const float4*)(X + i + 4);
    bf16x8 o;
    o[0] = (__bf16)a.x; o[1] = (__bf16)a.y; o[2] = (__bf16)a.z; o[3] = (__bf16)a.w;
    o[4] = (__bf16)b.x; o[5] = (__bf16)b.y; o[6] = (__bf16)b.z; o[7] = (__bf16)b.w;
    *(bf16x8*)(Xbf + i) = o;
}

// ---------------- step kernel ----------------

__device__ __forceinline__ float sigf(float x) {
    return __builtin_amdgcn_rcpf(1.0f + __expf(-x));
}
__device__ __forceinline__ float tanhf_fast(float x) {
    float ax = fabsf(x);
    float e  = __expf(-2.0f * ax);
    float r  = (1.0f - e) * __builtin_amdgcn_rcpf(1.0f + e);
    return copysignf(r, x);
}

template <bool XBF>
__global__ __launch_bounds__(256)
void step_kernel(int t,
                 const float* __restrict__ X, const __bf16* __restrict__ Xbf,
                 const __bf16* __restrict__ Wt, const __bf16* __restrict__ WqhT,
                 const float* __restrict__ bf_, const float* __restrict__ bi_,
                 const float* __restrict__ bu_, const float* __restrict__ bo_,
                 const float* __restrict__ bq_, const float* __restrict__ bqh_,
                 const float* __restrict__ thf, const float* __restrict__ thi,
                 const float* __restrict__ thu, const float* __restrict__ tho,
                 __bf16* __restrict__ hxbf, float* __restrict__ cx,
                 float* __restrict__ out)
{
    const int j    = blockIdx.x;   // h-block: h in [16j, 16j+16)
    const int rb   = blockIdx.y;   // rows [64rb, 64rb+64)
    const int tid  = threadIdx.x;
    const int w    = tid >> 6;     // wave 0..3 -> rows 16w..16w+15
    const int l    = tid & 63;
    const int lrow = l & 15;
    const int lk   = l >> 4;       // 0..3

    const int ar = rb * 64 + w * 16 + lrow;   // A row (batch index)

    f32x4 acc[5] = {};   // 4 gate tiles (f,i,u,o) + q tile

    // B fragment row pointers (Wt is N x K, k-contiguous), include lane k offset
    const __bf16* bp0 = Wt + (size_t)(j * 64 + 0  + lrow) * KDIM + lk * 8;
    const __bf16* bp1 = Wt + (size_t)(j * 64 + 16 + lrow) * KDIM + lk * 8;
    const __bf16* bp2 = Wt + (size_t)(j * 64 + 32 + lrow) * KDIM + lk * 8;
    const __bf16* bp3 = Wt + (size_t)(j * 64 + 48 + lrow) * KDIM + lk * 8;
    const __bf16* bp4 = Wt + (size_t)(2048     + lrow) * KDIM + lk * 8;

    // ---- K phase 1: x_t (k = 0..511) ----
    if (XBF) {
        const __bf16* aptr = Xbf + ((size_t)t * BATCH + ar) * DIM + lk * 8;
        #pragma unroll 4
        for (int ks = 0; ks < 16; ++ks) {
            bf16x8 a = *(const bf16x8*)(aptr + ks * 32);
            bf16x8 b0 = *(const bf16x8*)(bp0 + ks * 32);
            bf16x8 b1 = *(const bf16x8*)(bp1 + ks * 32);
            bf16x8 b2 = *(const bf16x8*)(bp2 + ks * 32);
            bf16x8 b3 = *(const bf16x8*)(bp3 + ks * 32);
            bf16x8 b4 = *(const bf16x8*)(bp4 + ks * 32);
            acc[0] = __builtin_amdgcn_mfma_f32_16x16x32_bf16(a, b0, acc[0], 0, 0, 0);
            acc[1] = __builtin_amdgcn_mfma_f32_16x16x32_bf16(a, b1, acc[1], 0, 0, 0);
            acc[2] = __builtin_amdgcn_mfma_f32_16x16x32_bf16(a, b2, acc[2], 0, 0, 0);
            acc[3] = __builtin_amdgcn_mfma_f32_16x16x32_bf16(a, b3, acc[3], 0, 0, 0);
            acc[4] = __builtin_amdgcn_mfma_f32_16x16x32_bf16(a, b4, acc[4], 0, 0, 0);
        }
    } else {
        const float* aptr = X + ((size_t)t * BATCH + ar) * DIM + lk * 8;
        #pragma unroll 2
        for (int ks = 0; ks < 16; ++ks) {
            float4 x0 = *(const float4*)(aptr + ks * 32);
            float4 x1 = *(const float4*)(aptr + ks * 32 + 4);
            bf16x8 a;
            a[0] = (__bf16)x0.x; a[1] = (__bf16)x0.y; a[2] = (__bf16)x0.z; a[3] = (__bf16)x0.w;
            a[4] = (__bf16)x1.x; a[5] = (__bf16)x1.y; a[6] = (__bf16)x1.z; a[7] = (__bf16)x1.w;
            bf16x8 b0 = *(const bf16x8*)(bp0 + ks * 32);
            bf16x8 b1 = *(const bf16x8*)(bp1 + ks * 32);
            bf16x8 b2 = *(const bf16x8*)(bp2 + ks * 32);
            bf16x8 b3 = *(const bf16x8*)(bp3 + ks * 32);
            bf16x8 b4 = *(const bf16x8*)(bp4 + ks * 32);
            acc[0] = __builtin_amdgcn_mfma_f32_16x16x32_bf16(a, b0, acc[0], 0, 0, 0);
            acc[1] = __builtin_amdgcn_mfma_f32_16x16x32_bf16(a, b1, acc[1], 0, 0, 0);
            acc[2] = __builtin_amdgcn_mfma_f32_16x16x32_bf16(a, b2, acc[2], 0, 0, 0);
            acc[3] = __builtin_amdgcn_mfma_f32_16x16x32_bf16(a, b3, acc[3], 0, 0, 0);
            acc[4] = __builtin_amdgcn_mfma_f32_16x16x32_bf16(a, b4, acc[4], 0, 0, 0);
        }
    }

    // ---- K phase 2: hx (k = 512..1023), hx stored bf16 ----
    {
        const __bf16* aptr = hxbf + (size_t)ar * HID + lk * 8;
        #pragma unroll 4
        for (int ks = 0; ks < 16; ++ks) {
            bf16x8 a = *(const bf16x8*)(aptr + ks * 32);
            bf16x8 b0 = *(const bf16x8*)(bp0 + 512 + ks * 32);
            bf16x8 b1 = *(const bf16x8*)(bp1 + 512 + ks * 32);
            bf16x8 b2 = *(const bf16x8*)(bp2 + 512 + ks * 32);
            bf16x8 b3 = *(const bf16x8*)(bp3 + 512 + ks * 32);
            bf16x8 b4 = *(const bf16x8*)(bp4 + 512 + ks * 32);
            acc[0] = __builtin_amdgcn_mfma_f32_16x16x32_bf16(a, b0, acc[0], 0, 0, 0);
            acc[1] = __builtin_amdgcn_mfma_f32_16x16x32_bf16(a, b1, acc[1], 0, 0, 0);
            acc[2] = __builtin_amdgcn_mfma_f32_16x16x32_bf16(a, b2, acc[2], 0, 0, 0);
            acc[3] = __builtin_amdgcn_mfma_f32_16x16x32_bf16(a, b3, acc[3], 0, 0, 0);
            acc[4] = __builtin_amdgcn_mfma_f32_16x16x32_bf16(a, b4, acc[4], 0, 0, 0);
        }
    }

    // ---- epilogue: q-layer (cumprod of cos) + 4 masked MFMAs + cell update ----
    __shared__ __align__(16) float          qin[64][8];
    __shared__ __align__(16) unsigned short cumbf[64][4][8];

    // scatter q_in C-frag (acc[4], valid cols 0..7) to LDS; D row = lk*4+r, col = lrow
    if (lrow < 8) {
        #pragma unroll
        for (int r = 0; r < 4; ++r)
            qin[w * 16 + lk * 4 + r][lrow] = acc[4][r];
    }
    __syncthreads();

    // each lane: one (row, gate): 8 cos + cumprod, write bf16x8
    {
        const int row = w * 16 + lrow;
        const int g   = lk;
        const float* th = (g == 0) ? thf : (g == 1) ? thi : (g == 2) ? thu : tho;
        float cp = 1.0f;
        bf16x8 cv;
        #pragma unroll
        for (int q = 0; q < 8; ++q) {
            float qv = qin[row][q] + bq_[q] + th[q];
            cp *= __cosf(qv);
            cv[q] = (__bf16)cp;
        }
        *(bf16x8*)(&cumbf[row][g][0]) = cv;
    }
    __syncthreads();

    // A2-frag: lane l -> cum[row=16w+(l&15)][gate=l>>4][w=0..7] : exact A-layout match
    bf16x8 a2 = *(const bf16x8*)(&cumbf[w * 16 + lrow][lk][0]);
    bf16x8 wq = *(const bf16x8*)(WqhT + (size_t)(j * 16 + lrow) * 8);
    bf16x8 zv = {};
    f32x4 vacc[4];
    #pragma unroll
    for (int g = 0; g < 4; ++g) {
        bf16x8 bg = (lk == g) ? wq : zv;   // block-diagonal B: isolate gate g's K rows
        f32x4 z = {};
        vacc[g] = __builtin_amdgcn_mfma_f32_16x16x32_bf16(a2, bg, z, 0, 0, 0);
    }

    const int   h   = j * 16 + lrow;
    const float bfv = bf_[h], biv = bi_[h], buv = bu_[h], bov = bo_[h], bqv = bqh_[h];

    #pragma unroll
    for (int r = 0; r < 4; ++r) {
        const int    b  = rb * 64 + w * 16 + lk * 4 + r;
        const size_t ch = (size_t)b * HID + h;
        float f  = ALPHA_C * sigf(acc[0][r] + bfv) + (1.0f - ALPHA_C) * sigf(vacc[0][r] + bqv);
        float i_ = ALPHA_C * sigf(acc[1][r] + biv) + (1.0f - ALPHA_C) * sigf(vacc[1][r] + bqv);
        float g_ = ALPHA_C * tanhf_fast(acc[2][r] + buv) + (1.0f - ALPHA_C) * tanhf_fast(vacc[2][r] + bqv);
        float o_ = ALPHA_C * sigf(acc[3][r] + bov) + (1.0f - ALPHA_C) * sigf(vacc[3][r] + bqv);
        float cn = f * cx[ch] + i_ * g_;
        float hn = o_ * tanhf_fast(cn);
        cx[ch]   = cn;
        hxbf[ch] = (__bf16)hn;
        out[(size_t)t * (BATCH * HID) + ch] = hn;
    }
}

// ---------------- launch ----------------

extern "C" void kernel_launch(void* const* d_in, const int* in_sizes, int n_in,
                              void* d_out, int out_size, void* d_ws, size_t ws_size,
                              hipStream_t stream) {
    const float* X   = (const float*)d_in[0];
    const float* Wf  = (const float*)d_in[1];
    const float* bf_ = (const float*)d_in[2];
    const float* Wi  = (const float*)d_in[3];
    const float* bi  = (const float*)d_in[4];
    const float* Wu  = (const float*)d_in[5];
    const float* bu  = (const float*)d_in[6];
    const float* Wo  = (const float*)d_in[7];
    const float* bo  = (const float*)d_in[8];
    const float* Wq  = (const float*)d_in[9];
    const float* bq  = (const float*)d_in[10];
    const float* Wqh = (const float*)d_in[11];
    const float* bqh = (const float*)d_in[12];
    const float* thf = (const float*)d_in[13];
    const float* thi = (const float*)d_in[14];
    const float* thu = (const float*)d_in[15];
    const float* tho = (const float*)d_in[16];
    float* out = (float*)d_out;

    char*  ws  = (char*)d_ws;
    size_t off = 0;
    auto alloc = [&](size_t bytes) -> char* {
        char* p = ws + off;
        off += (bytes + 255) & ~(size_t)255;
        return p;
    };
    __bf16* Wt   = (__bf16*)alloc((size_t)NPACK * KDIM * 2);
    __bf16* WqhT = (__bf16*)alloc((size_t)HID * NQV * 2);
    float*  cx   = (float*) alloc((size_t)BATCH * HID * 4);
    __bf16* hxbf = (__bf16*)alloc((size_t)BATCH * HID * 2);
    size_t base_end  = off;
    size_t xbf_bytes = (size_t)T_STEPS * BATCH * DIM * 2;
    bool   use_xbf   = (ws_size >= base_end + xbf_bytes);
    __bf16* Xbf = use_xbf ? (__bf16*)alloc(xbf_bytes) : nullptr;

    // init state (ws is poisoned 0xAA before every call)
    zero_kernel<<<dim3((BATCH * HID) / 256), dim3(256), 0, stream>>>((uint32_t*)cx, BATCH * HID);
    zero_kernel<<<dim3((BATCH * HID / 2) / 256), dim3(256), 0, stream>>>((uint32_t*)hxbf, BATCH * HID / 2);

    pack_w_kernel<<<dim3((NPACK * KDIM) / 256), dim3(256), 0, stream>>>(Wf, Wi, Wu, Wo, Wq, Wt);
    pack_wqh_kernel<<<dim3((HID * NQV + 255) / 256), dim3(256), 0, stream>>>(Wqh, WqhT);
    if (use_xbf)
        cvt_x_kernel<<<dim3((int)((size_t)T_STEPS * BATCH * DIM / 2048)), dim3(256), 0, stream>>>(X, Xbf);

    dim3 grid(32, 8), block(256);
    if (use_xbf) {
        for (int t = 0; t < T_STEPS; ++t)
            step_kernel<true><<<grid, block, 0, stream>>>(t, X, Xbf, Wt, WqhT,
                bf_, bi, bu, bo, bq, bqh, thf, thi, thu, tho, hxbf, cx, out);
    } else {
        for (int t = 0; t < T_STEPS; ++t)
            step_kernel<false><<<grid, block, 0, stream>>>(t, X, Xbf, Wt, WqhT,
                bf_, bi, bu, bo, bq, bqh, thf, thi, thu, tho, hxbf, cx, out);
    }

    // tail outputs: hx = out[T-1], cx
    const size_t BH = (size_t)BATCH * HID;
    hipMemcpyAsync(out + (size_t)T_STEPS * BH, out + (size_t)(T_STEPS - 1) * BH,
                   BH * sizeof(float), hipMemcpyDeviceToDevice, stream);
    hipMemcpyAsync(out + (size_t)T_STEPS * BH + BH, cx,
                   BH * sizeof(float), hipMemcpyDeviceToDevice, stream);
    (void)in_sizes; (void)n_in; (void)out_size;
}